// Round 4
// baseline (153.575 us; speedup 1.0000x reference)
//
#include <hip/hip_runtime.h>
#include <hip/hip_bf16.h>
#include <math.h>

#define B_ 4
#define S_ 2048
#define E_ 1024
#define H_ 64
#define NQT 32          // S/64 q-tiles
#define SPLITS 8
#define TPS 4           // 64-key tiles per split (256 keys/split)
#define SENT (-1.25e8f) // masked-logit sentinel (= -1e9 * 0.125)

typedef short bf16x8 __attribute__((ext_vector_type(8)));
typedef float f32x4 __attribute__((ext_vector_type(4)));
typedef unsigned short U16;
typedef U16 u16x8 __attribute__((ext_vector_type(8)));
typedef U16 u16x4 __attribute__((ext_vector_type(4)));

__device__ __forceinline__ U16 f2bf(float f){
    unsigned u = __builtin_bit_cast(unsigned, f);
    u += 0x7fffu + ((u >> 16) & 1u);          // RNE
    return (U16)(u >> 16);
}
__device__ __forceinline__ float bf2f(U16 h){
    return __builtin_bit_cast(float, ((unsigned)h) << 16);
}
#define MFMA16(a,b,c) __builtin_amdgcn_mfma_f32_16x16x32_bf16((a),(b),(c),0,0,0)

typedef const __attribute__((address_space(1))) void GvPtr;
typedef __attribute__((address_space(3))) void LdsPtr;
__device__ __forceinline__ void gload_lds16(const void* g, void* l){
    __builtin_amdgcn_global_load_lds((GvPtr*)g, (LdsPtr*)l, 16, 0, 0);
}

// ---------------------------------------------------------------------------
// Kernel 0: split W (3 comps, fp32) into hi/lo bf16 pair arrays.
// ---------------------------------------------------------------------------
__global__ __launch_bounds__(256) void prep_w(
    const float* __restrict__ Wq, const float* __restrict__ Wk,
    const float* __restrict__ Wv, U16* __restrict__ Whi, U16* __restrict__ Wlo)
{
    int i4 = (blockIdx.x*256 + threadIdx.x) * 4;     // < 3*65536
    int c = i4 >> 16, rem = i4 & 65535;
    const float* src = (c==0) ? Wq : (c==1) ? Wk : Wv;
    float4 v = *(const float4*)(src + rem);
    float a[4] = {v.x, v.y, v.z, v.w};
    u16x4 hv, lv;
    #pragma unroll
    for (int j=0;j<4;j++){ U16 h = f2bf(a[j]); hv[j]=h; lv[j]=f2bf(a[j]-bf2f(h)); }
    *(u16x4*)(Whi + i4) = hv;
    *(u16x4*)(Wlo + i4) = lv;
}

// ---------------------------------------------------------------------------
// Kernel 1: QKV projection. Grid (128 m-tiles of 64, 3 comps) = 384 blocks,
// 256 thr = 4 waves; wave = k-quarter (256 k). NO LDS / barriers in main loop:
// x read as fp32 A-frags (16x128B segments), converted hi/lo in-reg; W read as
// pre-split bf16 B-frags straight from L2. Double-buffered 32-k steps.
// Cross-wave k-reduce via LDS epilogue. mt=4 x nt=4 acc.
// ---------------------------------------------------------------------------
__global__ __launch_bounds__(256, 2) void qkv_kernel(
    const float* __restrict__ x, const U16* __restrict__ Whi_g,
    const U16* __restrict__ Wlo_g,
    U16* __restrict__ Qhi, U16* __restrict__ Qlo,
    U16* __restrict__ Khi, U16* __restrict__ Klo, U16* __restrict__ Vt)
{
    __shared__ __align__(16) float Red[4*16*64*4];   // 64 KB, epilogue only
    const int m0 = blockIdx.x * 64;
    const int comp = blockIdx.y;
    const int tid = threadIdx.x, lane = tid & 63, wv = tid >> 6;
    const int l15 = lane & 15, quad = lane >> 4;
    const int kq0 = wv * 256;                        // this wave's k-quarter

    f32x4 acc[4][4];
    #pragma unroll
    for (int mt=0;mt<4;mt++)
    #pragma unroll
    for (int nt=0;nt<4;nt++) acc[mt][nt] = f32x4{0.f,0.f,0.f,0.f};

    const float* xb = x + (size_t)(m0 + l15)*E_ + kq0 + quad*8;
    const U16* whb = Whi_g + (size_t)comp*65536 + (size_t)l15*E_ + kq0 + quad*8;
    const U16* wlb = Wlo_g + (size_t)comp*65536 + (size_t)l15*E_ + kq0 + quad*8;

    float4 xf[2][4][2];          // [buf][mt][half]
    bf16x8 wh[2][4], wl[2][4];   // [buf][nt]

    auto loadstep = [&](int s, int buf){
        #pragma unroll
        for (int mt=0;mt<4;mt++){
            const float* p = xb + (size_t)mt*16*E_ + s*32;
            xf[buf][mt][0] = ((const float4*)p)[0];
            xf[buf][mt][1] = ((const float4*)p)[1];
        }
        #pragma unroll
        for (int nt=0;nt<4;nt++){
            wh[buf][nt] = *(const bf16x8*)(whb + (size_t)nt*16*E_ + s*32);
            wl[buf][nt] = *(const bf16x8*)(wlb + (size_t)nt*16*E_ + s*32);
        }
    };

    loadstep(0, 0);
    #pragma unroll
    for (int s=0; s<8; ++s){
        const int buf = s & 1;
        if (s < 7) loadstep(s+1, buf^1);
        bf16x8 ah[4], al[4];
        #pragma unroll
        for (int mt=0;mt<4;mt++){
            const float4 a = xf[buf][mt][0], b2 = xf[buf][mt][1];
            float v[8] = {a.x,a.y,a.z,a.w,b2.x,b2.y,b2.z,b2.w};
            #pragma unroll
            for (int j=0;j<8;j++){
                U16 h = f2bf(v[j]);
                ah[mt][j] = (short)h;
                al[mt][j] = (short)f2bf(v[j] - bf2f(h));
            }
        }
        #pragma unroll
        for (int mt=0;mt<4;mt++)
        #pragma unroll
        for (int nt=0;nt<4;nt++){
            acc[mt][nt] = MFMA16(ah[mt], wh[buf][nt], acc[mt][nt]);  // hi*hi
            acc[mt][nt] = MFMA16(ah[mt], wl[buf][nt], acc[mt][nt]);  // hi*lo
            acc[mt][nt] = MFMA16(al[mt], wh[buf][nt], acc[mt][nt]);  // lo*hi
        }
    }

    // cross-wave (k-quarter) reduce via LDS
    #pragma unroll
    for (int mt=0;mt<4;mt++)
    #pragma unroll
    for (int nt=0;nt<4;nt++)
        *(f32x4*)&Red[(((wv*16) + (mt*4+nt))*64 + lane)*4] = acc[mt][nt];
    __syncthreads();

    #pragma unroll
    for (int pp=0; pp<4; ++pp){
        const int pair = wv*4 + pp, mt = pair >> 2, nt = pair & 3;
        f32x4 sum = *(const f32x4*)&Red[((0*16 + pair)*64 + lane)*4];
        #pragma unroll
        for (int w2=1; w2<4; ++w2)
            sum += *(const f32x4*)&Red[((w2*16 + pair)*64 + lane)*4];
        const int h = nt*16 + l15;
        const int row = m0 + mt*16 + quad*4;
        if (comp == 0){
            #pragma unroll
            for (int r=0;r<4;r++){
                float vv = sum[r]; U16 hh = f2bf(vv);
                Qhi[(size_t)(row+r)*H_ + h] = hh;
                Qlo[(size_t)(row+r)*H_ + h] = f2bf(vv - bf2f(hh));
            }
        } else if (comp == 1){
            #pragma unroll
            for (int r=0;r<4;r++){
                float vv = sum[r]; U16 hh = f2bf(vv);
                Khi[(size_t)(row+r)*H_ + h] = hh;
                Klo[(size_t)(row+r)*H_ + h] = f2bf(vv - bf2f(hh));
            }
        } else {
            const int b = row >> 11, s0 = row & (S_-1);
            u16x4 pk;
            #pragma unroll
            for (int r=0;r<4;r++) pk[r] = f2bf(sum[r]);
            *(u16x4*)(Vt + ((size_t)b*H_ + h)*S_ + s0) = pk;  // V^T [b][h][s]
        }
    }
}

// ---------------------------------------------------------------------------
// Kernel 2: flash attention, split-K, S^T form. Single LDS buffer (34 KB ->
// 4 blocks/CU) + source-permuted global_load_lds staging (swizzled, conflict-
// free frag reads). Lane owns one q-row: 4 shuffles per softmax.
// ---------------------------------------------------------------------------
__global__ __launch_bounds__(256) void attn_kernel(
    const U16* __restrict__ Qhi, const U16* __restrict__ Qlo,
    const U16* __restrict__ Khi, const U16* __restrict__ Klo,
    const U16* __restrict__ Vt, const int* __restrict__ pad,
    float* __restrict__ Opart, float* __restrict__ mpart, float* __restrict__ lpart)
{
    const int qt = blockIdx.x, b = blockIdx.y, sp = blockIdx.z;
    const int t0 = sp * TPS;
    if (t0 > qt) return;
    const int t1 = min(t0 + TPS, qt + 1);

    __shared__ __align__(16) U16 KtH[64*64], KtL[64*64], Vts[64*64];
    __shared__ __align__(16) U16 Ps[4][16*80];   // per-wave P[q=16][key 64], stride 80

    const int tid = threadIdx.x, lane = tid & 63, wv = tid >> 6;
    const int l15 = lane & 15, quad = lane >> 4;

    // Q fragments as B-operand (lane l15 = q-row, k = d = quad*8+j)
    const size_t qrow = (size_t)b*S_ + qt*64 + wv*16 + l15;
    bf16x8 aqh0 = *(const bf16x8*)(Qhi + qrow*H_ + quad*8);
    bf16x8 aqh1 = *(const bf16x8*)(Qhi + qrow*H_ + 32 + quad*8);
    bf16x8 aql0 = *(const bf16x8*)(Qlo + qrow*H_ + quad*8);
    bf16x8 aql1 = *(const bf16x8*)(Qlo + qrow*H_ + 32 + quad*8);

    float m_i = -INFINITY, l_i = 0.f;
    f32x4 o[4];
    #pragma unroll
    for (int i=0;i<4;i++) o[i] = f32x4{0.f,0.f,0.f,0.f};
    const int qg = qt*64 + wv*16 + l15;
    U16* Pw = &Ps[wv][0];
    const int sw = l15 & 7;

    for (int t = t0; t < t1; ++t) {
        const int kb = t * 64;
        __syncthreads();                      // previous iteration's LDS reads done
        {   // stage K hi/lo + V^T tile, source-permuted so LDS is pre-swizzled
            const U16* khp = Khi + ((size_t)b*S_ + kb)*H_;
            const U16* klp = Klo + ((size_t)b*S_ + kb)*H_;
            #pragma unroll
            for (int ch=0; ch<2; ++ch){
                const int sb = wv*128 + ch*64;
                const int u = sb + lane;
                const int row = u >> 3, g = u & 7, gs = g ^ (row & 7);
                gload_lds16(khp + (size_t)row*H_ + gs*8, KtH + sb*8);
                gload_lds16(klp + (size_t)row*H_ + gs*8, KtL + sb*8);
                gload_lds16(Vt + ((size_t)b*H_ + row)*S_ + kb + gs*8, Vts + sb*8);
            }
        }
        const int pv = pad[(size_t)b*S_ + kb + lane];
        const unsigned long long pm = __ballot(pv != 0);
        __syncthreads();                      // vmcnt drained -> staging landed

        // --- S^T = K Q^T (hi/lo, fp32-accurate logits) ---
        f32x4 z[4];
        #pragma unroll
        for (int nt=0; nt<4; nt++){
            const int kr = (nt*16 + l15)*8;
            bf16x8 kh0 = ((const bf16x8*)KtH)[kr + (quad ^ sw)];
            bf16x8 kh1 = ((const bf16x8*)KtH)[kr + ((4+quad) ^ sw)];
            bf16x8 kl0 = ((const bf16x8*)KtL)[kr + (quad ^ sw)];
            bf16x8 kl1 = ((const bf16x8*)KtL)[kr + ((4+quad) ^ sw)];
            f32x4 zz = f32x4{0.f,0.f,0.f,0.f};
            zz = MFMA16(kh0, aqh0, zz);
            zz = MFMA16(kh1, aqh1, zz);
            zz = MFMA16(kh0, aql0, zz);
            zz = MFMA16(kh1, aql1, zz);
            zz = MFMA16(kl0, aqh0, zz);
            zz = MFMA16(kl1, aqh1, zz);
            z[nt] = zz;
        }
        // --- mask + scale ---
        float rmax = -INFINITY;
        #pragma unroll
        for (int nt=0; nt<4; nt++){
            const int rel = qg - kb - nt*16 - quad*4;
            const unsigned mb = (unsigned)(pm >> (nt*16 + quad*4)) & 0xFu;
            #pragma unroll
            for (int r=0;r<4;r++){
                const bool ok = (r <= rel) && ((mb >> r) & 1u);
                const float v = ok ? z[nt][r]*0.125f : SENT;
                z[nt][r] = v;
                rmax = fmaxf(rmax, v);
            }
        }
        rmax = fmaxf(rmax, __shfl_xor(rmax, 16));
        rmax = fmaxf(rmax, __shfl_xor(rmax, 32));
        const float mn = fmaxf(m_i, rmax);
        const float alpha = __expf(m_i - mn);
        m_i = mn;
        float rsum = 0.f;
        #pragma unroll
        for (int nt=0; nt<4; nt++)
        #pragma unroll
        for (int r=0;r<4;r++){
            const float pe = __expf(z[nt][r] - mn);
            z[nt][r] = pe;
            rsum += pe;
        }
        rsum += __shfl_xor(rsum, 16);
        rsum += __shfl_xor(rsum, 32);
        l_i = l_i*alpha + rsum;
        #pragma unroll
        for (int nt=0; nt<4; nt++)
        #pragma unroll
        for (int r=0;r<4;r++) o[nt][r] *= alpha;

        // --- P -> per-wave LDS row-major [q=l15][key] ---
        #pragma unroll
        for (int nt=0; nt<4; nt++){
            u16x4 pk;
            #pragma unroll
            for (int r=0;r<4;r++) pk[r] = f2bf(z[nt][r]);
            *(u16x4*)(Pw + l15*80 + nt*16 + quad*4) = pk;
        }
        // --- O^T += V^T P^T ---
        #pragma unroll
        for (int ks=0; ks<2; ks++){
            bf16x8 bp = *(const bf16x8*)(Pw + l15*80 + ks*32 + quad*8);
            #pragma unroll
            for (int nt=0; nt<4; nt++){
                bf16x8 av = ((const bf16x8*)Vts)[(nt*16 + l15)*8 + ((ks*4+quad) ^ sw)];
                o[nt] = MFMA16(av, bp, o[nt]);
            }
        }
    }
    // partials: row = [b][qt][sp][q 64], cols h
    const size_t rbase = ((size_t)((b*NQT + qt)*SPLITS + sp))*64 + wv*16 + l15;
    if (quad == 0) { mpart[rbase] = m_i; lpart[rbase] = l_i; }
    #pragma unroll
    for (int nt=0; nt<4; nt++)
        *((f32x4*)(Opart + rbase*H_ + nt*16 + quad*4)) = o[nt];
}

// ---------------------------------------------------------------------------
// Kernel 3: merge split-K partials; inline mean-of-V for fully-masked rows.
// ---------------------------------------------------------------------------
__global__ __launch_bounds__(256) void combine_kernel(
    const float* __restrict__ Opart, const float* __restrict__ mpart,
    const float* __restrict__ lpart, const U16* __restrict__ Vt,
    float* __restrict__ out)
{
    const int idx = blockIdx.x*256 + threadIdx.x;
    const int h = idx & 63;
    const int q = (idx >> 6) & (S_-1);
    const int b = idx >> 17;
    const int qt = q >> 6, r = q & 63;
    const int ns = (qt >> 2) + 1;
    const size_t rb = ((size_t)(b*NQT + qt)*SPLITS)*64 + r;
    float M = -INFINITY;
    for (int s2=0; s2<ns; s2++) M = fmaxf(M, mpart[rb + (size_t)s2*64]);
    float res;
    if (M == SENT) {
        const U16* vsrc = Vt + ((size_t)b*H_ + h)*S_;
        float sm = 0.f;
        for (int s=0; s<S_; ++s) sm += bf2f(vsrc[s]);
        res = sm * (1.f/(float)S_);
    } else {
        float L = 0.f, accv = 0.f;
        for (int s2=0; s2<ns; s2++){
            const float mi = mpart[rb + (size_t)s2*64];
            const float w = __expf(mi - M);
            L    += w * lpart[rb + (size_t)s2*64];
            accv += w * Opart[(rb + (size_t)s2*64)*H_ + h];
        }
        res = accv / L;
    }
    out[idx] = res;
}

// ---------------------------------------------------------------------------
// Workspace: Whi 0 (384K) | Wlo 384K | Qhi 1M | Qlo 2M | Khi 3M | Klo 4M |
//            Vt 5M | Opart 6M (16M) | mpart 22M | lpart 22.25M
// ---------------------------------------------------------------------------
extern "C" void kernel_launch(void* const* d_in, const int* in_sizes, int n_in,
                              void* d_out, int out_size, void* d_ws, size_t ws_size,
                              hipStream_t stream)
{
    (void)in_sizes; (void)n_in; (void)out_size; (void)ws_size;
    const float* x  = (const float*)d_in[0];
    const int* pad  = (const int*)d_in[1];
    const float* Wq = (const float*)d_in[2];
    const float* Wk = (const float*)d_in[3];
    const float* Wv = (const float*)d_in[4];
    float* out = (float*)d_out;
    char* ws = (char*)d_ws;
    const size_t MB = 1u << 20;
    U16* Whi = (U16*)(ws);
    U16* Wlo = (U16*)(ws + 393216);
    U16* Qhi = (U16*)(ws + 1*MB);
    U16* Qlo = (U16*)(ws + 2*MB);
    U16* Khi = (U16*)(ws + 3*MB);
    U16* Klo = (U16*)(ws + 4*MB);
    U16* Vt  = (U16*)(ws + 5*MB);
    float* Opart = (float*)(ws + 6*MB);
    float* mpart = (float*)(ws + 22*MB);
    float* lpart = (float*)(ws + 22*MB + (1u<<18));

    prep_w<<<dim3(192), 256, 0, stream>>>(Wq, Wk, Wv, Whi, Wlo);
    qkv_kernel<<<dim3(128, 3), 256, 0, stream>>>(x, Whi, Wlo, Qhi, Qlo, Khi, Klo, Vt);
    attn_kernel<<<dim3(NQT, B_, SPLITS), 256, 0, stream>>>(Qhi, Qlo, Khi, Klo, Vt, pad,
                                                           Opart, mpart, lpart);
    combine_kernel<<<dim3((B_*S_*H_)/256), 256, 0, stream>>>(Opart, mpart, lpart, Vt, out);
}